// Round 3
// baseline (146.352 us; speedup 1.0000x reference)
//
#include <hip/hip_runtime.h>

// ColumnConsistencyLoss: B=16, T=8192, C=128.
// out = mean over columns c with n_c>1 of (q_c - t_c/n_c)/(n_c*C)
//   n_c = # valid rows with seg=c
//   q_c = sum over those rows of ||softmax(row)||^2 = sum (z2/z^2)
//   s[c][j] = sum over those rows of p_j ; t_c = sum_j s[c][j]^2
// No max-subtraction: logits ~ N(0,1), exp cannot overflow.

#define NROWS 131072          // B*T
#define CC    128             // columns
#define NB    256             // blocks in accumulation kernel (1 per CU)
#define BLK   1024            // 16 waves per block
#define WPB   16              // waves per block
#define RPB   (NROWS / NB)    // rows per block = 512
#define RPW   (RPB / WPB)     // rows per wave = 32 (two groups of 16)

// ---------------- Kernel 1: softmax + segmented accumulation ----------------
// 4 lanes per row: lane = 4*r + cl, r=row-in-group(0..15), cl=col-quarter.
// KEY (round-3): ALL global loads (masks, segs, and BOTH row-groups' 8x
// float4 logits) are issued before any exp/reduce work, so ~16 dwordx4 per
// lane are in flight at once. exp overwrites x[] in place to bound VGPRs.
// __launch_bounds__(1024,4): VGPR cap 128, keeps 16 waves/CU.

__device__ __forceinline__ void process_group(
    int v, int c, float4* x, int r, int cl,
    float* __restrict__ s_lds, float* __restrict__ n_lds,
    float* __restrict__ q_lds) {
  if (!v) return;  // uniform across the 4 lanes of a quad -> shfl below safe
  float z = 0.f, z2 = 0.f;
#pragma unroll
  for (int k = 0; k < 8; ++k) {
    float4 e;
    e.x = __expf(x[k].x); e.y = __expf(x[k].y);
    e.z = __expf(x[k].z); e.w = __expf(x[k].w);
    x[k] = e;  // in place: keeps register pressure flat
    z  += (e.x + e.y) + (e.z + e.w);
    z2 += (e.x * e.x + e.y * e.y) + (e.z * e.z + e.w * e.w);
  }
  z  += __shfl_xor(z, 1, 64);
  z2 += __shfl_xor(z2, 1, 64);
  z  += __shfl_xor(z, 2, 64);
  z2 += __shfl_xor(z2, 2, 64);
  const float inv = 1.0f / z;
  float* srow = s_lds + c * CC;
#pragma unroll
  for (int k = 0; k < 8; ++k) {
    const int kk = (k + r) & 7;          // staggered chunk (matches load)
    const int cb = kk * 16 + cl * 4;
    atomicAdd(&srow[cb + 0], x[k].x * inv);
    atomicAdd(&srow[cb + 1], x[k].y * inv);
    atomicAdd(&srow[cb + 2], x[k].z * inv);
    atomicAdd(&srow[cb + 3], x[k].w * inv);
  }
  if (cl == 0) {
    atomicAdd(&n_lds[c], 1.0f);
    atomicAdd(&q_lds[c], z2 * inv * inv);
  }
}

template <bool SLAB>
__global__ __launch_bounds__(BLK, 4) void accum_kernel(
    const float* __restrict__ logits, const int* __restrict__ seg,
    const int* __restrict__ mask, float* __restrict__ ws) {
  __shared__ float s_lds[CC * CC];   // 64 KiB
  __shared__ float n_lds[CC];
  __shared__ float q_lds[CC];
  for (int i = threadIdx.x; i < CC * CC; i += BLK) s_lds[i] = 0.f;
  if (threadIdx.x < CC) { n_lds[threadIdx.x] = 0.f; q_lds[threadIdx.x] = 0.f; }
  __syncthreads();

  const int wave = threadIdx.x >> 6;
  const int lane = threadIdx.x & 63;
  const int r    = lane >> 2;   // 0..15
  const int cl   = lane & 3;    // 0..3
  const int row0 = blockIdx.x * RPB + wave * RPW;
  const int row_a = row0 + r;
  const int row_b = row0 + 16 + r;

  // Issue every global load up front.
  const int va = mask[row_a];
  const int vb = mask[row_b];
  const int ca = seg[row_a];
  const int cb = seg[row_b];
  float4 xa[8], xb[8];
  {
    const float4* rpa = (const float4*)(logits + (size_t)row_a * CC);
    if (va) {
#pragma unroll
      for (int k = 0; k < 8; ++k) xa[k] = rpa[((k + r) & 7) * 4 + cl];
    }
    const float4* rpb = (const float4*)(logits + (size_t)row_b * CC);
    if (vb) {
#pragma unroll
      for (int k = 0; k < 8; ++k) xb[k] = rpb[((k + r) & 7) * 4 + cl];
    }
  }

  process_group(va, ca, xa, r, cl, s_lds, n_lds, q_lds);
  process_group(vb, cb, xb, r, cl, s_lds, n_lds, q_lds);
  __syncthreads();

  if (SLAB) {
    // slab_s: [NB][CC*CC]; slab_n/slab_q: [CC][NB]
    float4* dst = (float4*)(ws + (size_t)blockIdx.x * (CC * CC));
    const float4* src = (const float4*)s_lds;
    for (int i = threadIdx.x; i < CC * CC / 4; i += BLK) dst[i] = src[i];
    float* slab_n = ws + (size_t)NB * CC * CC;
    float* slab_q = slab_n + (size_t)CC * NB;
    if (threadIdx.x < CC) {
      slab_n[threadIdx.x * NB + blockIdx.x] = n_lds[threadIdx.x];
      slab_q[threadIdx.x * NB + blockIdx.x] = q_lds[threadIdx.x];
    }
  } else {
    float* s_g = ws;
    float* n_g = ws + CC * CC;
    float* q_g = n_g + CC;
    for (int i = threadIdx.x; i < CC * CC; i += BLK) {
      const float val = s_lds[i];
      if (val != 0.f) atomicAdd(&s_g[i], val);
    }
    if (threadIdx.x < CC && n_lds[threadIdx.x] != 0.f) {
      atomicAdd(&n_g[threadIdx.x], n_lds[threadIdx.x]);
      atomicAdd(&q_g[threadIdx.x], q_lds[threadIdx.x]);
    }
  }
}

// ---------------- Kernel 2 (slab path): reduce partials -> col_var[c] -------
// 128 blocks (one per c) x 1024 threads. Thread t: j = t&127, goff = t>>7;
// sums g = goff + 8*i (i=0..31): 32 independent coalesced scalar loads
// (each wave instruction covers 256 contiguous bytes).
#define K2T 1024
__global__ __launch_bounds__(K2T) void reduce_slab(
    const float* __restrict__ ws, float* __restrict__ colvar,
    float* __restrict__ flag) {
  const int c = blockIdx.x;
  const int t = threadIdx.x;
  const int j = t & 127;
  const int goff = t >> 7;             // 0..7
  const float* base = ws + (size_t)goff * (CC * CC) + (size_t)c * CC + j;
  float acc = 0.f;
#pragma unroll
  for (int i = 0; i < NB / 8; ++i)     // 32 loads, stride 8*64KB
    acc += base[(size_t)i * 8 * CC * CC];
  __shared__ float part[8 * CC];       // 4 KiB
  part[goff * CC + j] = acc;
  __syncthreads();

  float tp = 0.f, np = 0.f, qp = 0.f;
  if (t < CC) {
    float s = 0.f;
#pragma unroll
    for (int g8 = 0; g8 < 8; ++g8) s += part[g8 * CC + t];
    tp = s * s;
  } else if (t < 2 * CC) {
    const int g2 = t - CC;             // 0..127 -> covers g2 and g2+128
    const float* slab_n = ws + (size_t)NB * CC * CC;
    const float* slab_q = slab_n + (size_t)CC * NB;
    np = slab_n[c * NB + g2] + slab_n[c * NB + g2 + 128];
    qp = slab_q[c * NB + g2] + slab_q[c * NB + g2 + 128];
  }
#pragma unroll
  for (int off = 32; off > 0; off >>= 1) {
    tp += __shfl_xor(tp, off, 64);
    np += __shfl_xor(np, off, 64);
    qp += __shfl_xor(qp, off, 64);
  }
  __shared__ float fin[3 * (K2T / 64)];
  if ((t & 63) == 0) {
    const int w = t >> 6;
    fin[w * 3 + 0] = tp; fin[w * 3 + 1] = np; fin[w * 3 + 2] = qp;
  }
  __syncthreads();
  if (t == 0) {
    float tt = 0.f, nn = 0.f, qq = 0.f;
#pragma unroll
    for (int i = 0; i < K2T / 64; ++i) {
      tt += fin[i * 3 + 0]; nn += fin[i * 3 + 1]; qq += fin[i * 3 + 2];
    }
    float cv = 0.f, fl = 0.f;
    if (nn > 1.0f) {
      cv = (qq - tt / nn) / (nn * (float)CC);
      fl = 1.f;
    }
    colvar[c] = cv;
    flag[c] = fl;
  }
}

// ---------------- Kernel 2 (atomic fallback path) ---------------------------
__global__ __launch_bounds__(128) void reduce_atomic(
    const float* __restrict__ ws, float* __restrict__ colvar,
    float* __restrict__ flag) {
  const int c = blockIdx.x;
  const int j = threadIdx.x;
  const float* s_g = ws;
  const float* n_g = ws + CC * CC;
  const float* q_g = n_g + CC;
  const float s = s_g[c * CC + j];
  float t = s * s;
#pragma unroll
  for (int off = 32; off > 0; off >>= 1) t += __shfl_xor(t, off, 64);
  __shared__ float red[2];
  if ((j & 63) == 0) red[j >> 6] = t;
  __syncthreads();
  if (j == 0) {
    t = red[0] + red[1];
    const float n = n_g[c];
    const float q = q_g[c];
    float cv = 0.f, fl = 0.f;
    if (n > 1.0f) {
      cv = (q - t / n) / (n * (float)CC);
      fl = 1.f;
    }
    colvar[c] = cv;
    flag[c] = fl;
  }
}

// ---------------- Kernel 3: final scalar ------------------------------------
__global__ __launch_bounds__(128) void final_k(
    const float* __restrict__ colvar, const float* __restrict__ flag,
    float* __restrict__ out) {
  const int j = threadIdx.x;
  float cv = colvar[j];
  float fl = flag[j];
#pragma unroll
  for (int off = 32; off > 0; off >>= 1) {
    cv += __shfl_xor(cv, off, 64);
    fl += __shfl_xor(fl, off, 64);
  }
  __shared__ float red[4];
  if ((j & 63) == 0) {
    const int w = j >> 6;
    red[w * 2 + 0] = cv;
    red[w * 2 + 1] = fl;
  }
  __syncthreads();
  if (j == 0) {
    const float total = red[0] + red[2];
    const float count = red[1] + red[3];
    out[0] = (count > 0.f) ? total / fmaxf(count, 1.f) : 0.f;
  }
}

__global__ void zero_k(float* __restrict__ p, int n) {
  const int i = blockIdx.x * 256 + threadIdx.x;
  if (i < n) p[i] = 0.f;
}

extern "C" void kernel_launch(void* const* d_in, const int* in_sizes, int n_in,
                              void* d_out, int out_size, void* d_ws,
                              size_t ws_size, hipStream_t stream) {
  const float* logits = (const float*)d_in[0];  // (B,T,C) fp32
  const int* seg = (const int*)d_in[1];         // (B,T) int32
  const int* mask = (const int*)d_in[2];        // (B,T) int32 (bool 0/1)
  float* out = (float*)d_out;
  float* ws = (float*)d_ws;

  const size_t slab_floats =
      (size_t)NB * CC * CC + 2 * (size_t)CC * NB + 2 * CC;
  if (ws_size >= slab_floats * sizeof(float)) {
    float* colvar = ws + (size_t)NB * CC * CC + 2 * (size_t)CC * NB;
    float* flag = colvar + CC;
    accum_kernel<true><<<NB, BLK, 0, stream>>>(logits, seg, mask, ws);
    reduce_slab<<<CC, K2T, 0, stream>>>(ws, colvar, flag);
    final_k<<<1, 128, 0, stream>>>(colvar, flag, out);
  } else {
    const int nz = CC * CC + 2 * CC;
    float* colvar = ws + nz;
    float* flag = colvar + CC;
    zero_k<<<(nz + 255) / 256, 256, 0, stream>>>(ws, nz);
    accum_kernel<false><<<NB, BLK, 0, stream>>>(logits, seg, mask, ws);
    reduce_atomic<<<CC, 128, 0, stream>>>(ws, colvar, flag);
    final_k<<<1, 128, 0, stream>>>(colvar, flag, out);
  }
}